// Round 15
// baseline (384.652 us; speedup 1.0000x reference)
//
#include <hip/hip_runtime.h>
#include <hip/hip_bf16.h>

typedef unsigned short u16;
using short8  = __attribute__((ext_vector_type(8))) short;
using ushort8 = __attribute__((ext_vector_type(8))) unsigned short;
using float4v = __attribute__((ext_vector_type(4))) float;

#define N_POL  100000
#define N_TICK 20000
#define NNODE  120000
#define NEDGE  1000000
#define NREP   8        // count replicas (keyed by blockIdx&7 ~ XCD)
#define HB     977      // hist blocks: (NEDGE/4 + 255)/256
#define EB     3907     // fill blocks: (NEDGE+255)/256
#define POLB   50000    // N_POL/2
#define TICKB  10000    // N_TICK*128/256
// EMB=128, HID=256, OUT=128

static __device__ __forceinline__ float b2f(u16 u) {
    return __uint_as_float(((unsigned)u) << 16);
}
static __device__ __forceinline__ u16 f2b(float f) {
    unsigned u = __float_as_uint(f);
    unsigned r = (u + 0x7FFFu + ((u >> 16) & 1u)) >> 16;
    return (u16)r;
}
static __device__ __forceinline__ float lde(const void* p, size_t i, int f32) {
    return f32 ? ((const float*)p)[i] : b2f(((const u16*)p)[i]);
}

// MFMA B-fragment address for K=256, N=256 packed weights (verified R7):
// element (k,n) -> ((n/16)*8 + k/32)*512 + (((k>>3)&3)*16 + (n&15))*8 + (k&7)
static __device__ __forceinline__ size_t frag_addr(int k, int n) {
    return ((size_t)((n >> 4) * 8 + (k >> 5)) * 64 + (((k >> 3) & 3) * 16 + (n & 15))) * 8
           + (k & 7);
}

// 16B global->LDS DMA (wave-uniform LDS base; HW adds lane*16)
static __device__ __forceinline__ void gload_lds16(const u16* g, u16* l) {
    __builtin_amdgcn_global_load_lds(
        (const __attribute__((address_space(1))) void*)g,
        (__attribute__((address_space(3))) void*)l, 16, 0, 0);
}

// ---------------- detect dtype + zero count (merged; saves a dispatch) ------------
// Runtime input-dtype detection on edge_weight (uniform [0,1)). See R4/R5 notes.
__global__ __launch_bounds__(256) void detect_k(const void* __restrict__ ew,
                                                int* __restrict__ flag,
                                                int* __restrict__ count) {
    int i = blockIdx.x * 256 + threadIdx.x;
    if (i < NREP * NNODE) count[i] = 0;
    if (blockIdx.x == 0 && threadIdx.x == 0) {
        const u16* p = (const u16*)ew;
        int huge = 0, allz = 1;
        for (int j = 0; j < 128; j += 2) {
            u16 b = p[j];
            if (b != 0) allz = 0;
            float v = b2f(b);
            if (!(fabsf(v) <= 4.0f)) huge = 1;
        }
        *flag = huge | allz;
    }
}

// ---------------- hist_dst + build_x merged (independent; overlap) ----------------
// Blocks [0,HB): hist v11 — 4 edges/THREAD: one int4 dst load, 4 independent
// atomicAdds in flight together (4x atomic MLP per wave; r14 showed hist at
// 84us with all visible resources idle -> latency/queue-bound on the
// atomic-with-return round trip, 1 atomic per thread = MLP 1), one int4 rank
// store. Replicated count (blockIdx&7 ~ XCD) kept from r13 (+6us).
// Blocks [HB,..): build_x — streaming feature build backfills CU slots.
__global__ __launch_bounds__(256) void hist_build(const int* __restrict__ ei,
                                                  int* __restrict__ count,
                                                  int* __restrict__ rank,
                                                  const void* __restrict__ pf,
                                                  const int* __restrict__ sid,
                                                  const void* __restrict__ Wp,
                                                  const void* __restrict__ bp,
                                                  const void* __restrict__ semb,
                                                  const void* __restrict__ et,
                                                  const int* __restrict__ flag,
                                                  u16* __restrict__ Xb) {
    if (blockIdx.x < HB) {
        int rep = blockIdx.x & (NREP - 1);
        int* cbase = count + rep * NNODE;
        int e0 = (blockIdx.x * 256 + threadIdx.x) * 4;
        if (e0 + 4 <= NEDGE) {
            int4 d4 = *(const int4*)(ei + NEDGE + e0);
            int r0 = atomicAdd(&cbase[d4.x], 1);
            int r1 = atomicAdd(&cbase[d4.y], 1);
            int r2 = atomicAdd(&cbase[d4.z], 1);
            int r3 = atomicAdd(&cbase[d4.w], 1);
            int4 r4; r4.x = r0; r4.y = r1; r4.z = r2; r4.w = r3;
            *(int4*)(rank + e0) = r4;
        } else {
            for (int e = e0; e < NEDGE; e++)
                rank[e] = atomicAdd(&cbase[ei[NEDGE + e]], 1);
        }
        return;
    }
    const int f32 = *flag;
    int bb = blockIdx.x - HB;
    if (bb < POLB) {
        int row = bb * 2 + (threadIdx.x >> 7);
        int j = threadIdx.x & 127;
        float s = lde(bp, j, f32);
#pragma unroll
        for (int k = 0; k < 7; k++)
            s = fmaf(lde(pf, (size_t)row * 7 + k, f32), lde(Wp, k * 128 + j, f32), s);
        s = fmaxf(s, 0.f);
        s += lde(semb, (size_t)sid[row] * 128 + j, f32);
        Xb[(size_t)row * 128 + j] = f2b(s);
    } else {
        int idx = (bb - POLB) * 256 + threadIdx.x;
        Xb[(size_t)N_POL * 128 + idx] = f2b(lde(et, idx, f32));
    }
}

__global__ __launch_bounds__(256) void scan1(const int* __restrict__ count,
                                             int* __restrict__ roff,
                                             int* __restrict__ row_tmp,
                                             int* __restrict__ bsum) {
    __shared__ int sd[256];
    int t = threadIdx.x;
    int i = blockIdx.x * 256 + t;
    int c = 0;
    if (i < NNODE) {
#pragma unroll
        for (int r = 0; r < NREP; r++) {
            int v = count[r * NNODE + i];
            roff[r * NNODE + i] = c;     // prefix over replicas for this node
            c += v;
        }
    }
    sd[t] = c;
    __syncthreads();
#pragma unroll
    for (int off = 1; off < 256; off <<= 1) {
        int v = (t >= off) ? sd[t - off] : 0;
        __syncthreads();
        sd[t] += v;
        __syncthreads();
    }
    if (i < NNODE) row_tmp[i] = sd[t] - c;
    if (t == 255) bsum[blockIdx.x] = sd[t];
}

__global__ __launch_bounds__(512) void scan2(int* __restrict__ bsum, int nb) {
    __shared__ int sd[512];
    int t = threadIdx.x;
    int v = (t < nb) ? bsum[t] : 0;
    sd[t] = v;
    __syncthreads();
#pragma unroll
    for (int off = 1; off < 512; off <<= 1) {
        int u = (t >= off) ? sd[t - off] : 0;
        __syncthreads();
        sd[t] += u;
        __syncthreads();
    }
    if (t < nb) bsum[t] = sd[t] - v;
}

__global__ __launch_bounds__(256) void scan3(const int* __restrict__ row_tmp,
                                             const int* __restrict__ bsum,
                                             int* __restrict__ row_start) {
    int i = blockIdx.x * 256 + threadIdx.x;
    if (i < NNODE) row_start[i] = row_tmp[i] + bsum[blockIdx.x];
    if (i == 0) row_start[NNODE] = NEDGE;
}

// ---------------- fill_csr + prep_wf merged (independent; overlap) ----------------
// Blocks [0,EB): fill — atomic-free packed-edge scatter (critical path).
// Blocks [EB,EB+512): prep_wf — weight fragment packing backfills.
// NOTE: rep must match hist's mapping: hist block b owns edges [b*1024,(b+1)*1024)
// with rep=b&7, so for edge e: rep = (e>>10)&7.
__global__ __launch_bounds__(256) void fill_prep(const int* __restrict__ ei,
                                                 const void* __restrict__ ew,
                                                 const int* __restrict__ flag,
                                                 const int* __restrict__ row_start,
                                                 const int* __restrict__ roff,
                                                 const int* __restrict__ rank,
                                                 uint2* __restrict__ epk,
                                                 const void* __restrict__ W1rel,
                                                 const void* __restrict__ W1root,
                                                 const void* __restrict__ W2rel,
                                                 const void* __restrict__ W2root,
                                                 u16* __restrict__ Wf1,
                                                 u16* __restrict__ Wf2) {
    const int f32 = *flag;
    if (blockIdx.x < EB) {
        int e = blockIdx.x * 256 + threadIdx.x;
        if (e >= NEDGE) return;
        int rep = (e >> 10) & (NREP - 1);   // hist v11: 1024 edges per hist block
        int src = ei[e];
        int dst = ei[NEDGE + e];
        int pos = row_start[dst] + roff[rep * NNODE + dst] + rank[e];
        uint2 pk;
        pk.x = (unsigned)src;
        pk.y = (unsigned)f2b(lde(ew, e, f32));
        epk[pos] = pk;
        return;
    }
    int idx = (blockIdx.x - EB) * 256 + threadIdx.x;   // 0..131071
    int id = idx & 65535;
    int k = id >> 8, n = id & 255;
    if (idx < 65536) {
        float v = (k < 128) ? lde(W1rel, (size_t)k * 256 + n, f32)
                            : lde(W1root, (size_t)(k - 128) * 256 + n, f32);
        Wf1[frag_addr(k, n)] = f2b(v);
    } else {
        float v = (n < 128) ? lde(W2rel, (size_t)k * 128 + n, f32)
                            : lde(W2root, (size_t)k * 128 + (n - 128), f32);
        Wf2[frag_addr(k, n)] = f2b(v);
    }
}

// ---------------- gather1 (v8: packed edges; 4 edges/wave, 16B/lane) --------
__global__ __launch_bounds__(256) void gather128(const int* __restrict__ row_start,
                                                 const uint2* __restrict__ epk,
                                                 const u16* __restrict__ S,
                                                 u16* __restrict__ agg) {
    int n = blockIdx.x * 4 + (threadIdx.x >> 6);
    int lane = threadIdx.x & 63;
    int g4 = lane >> 4;        // edge slot 0..3
    int l16 = lane & 15;       // 16B chunk within the row
    int s0 = row_start[n], s1 = row_start[n + 1];
    float a[8] = {0.f, 0.f, 0.f, 0.f, 0.f, 0.f, 0.f, 0.f};
    int e = s0;
    for (; e + 8 <= s1; e += 8) {
        uint2 p0 = epk[e + g4], p1 = epk[e + 4 + g4];
        float w0 = b2f((u16)p0.y), w1 = b2f((u16)p1.y);
        ushort8 x0 = *(const ushort8*)(S + (size_t)p0.x * 128 + l16 * 8);
        ushort8 x1 = *(const ushort8*)(S + (size_t)p1.x * 128 + l16 * 8);
#pragma unroll
        for (int j = 0; j < 8; j++) {
            a[j] = fmaf(b2f(x0[j]), w0, a[j]);
            a[j] = fmaf(b2f(x1[j]), w1, a[j]);
        }
    }
    for (; e + 4 <= s1; e += 4) {
        uint2 p = epk[e + g4];
        float w = b2f((u16)p.y);
        ushort8 x = *(const ushort8*)(S + (size_t)p.x * 128 + l16 * 8);
#pragma unroll
        for (int j = 0; j < 8; j++) a[j] = fmaf(b2f(x[j]), w, a[j]);
    }
    if (e < s1) {
        int eg = e + g4;
        int valid = eg < s1;
        uint2 p = epk[valid ? eg : s0];    // s0 < s1 here, safe
        float w = valid ? b2f((u16)p.y) : 0.f;
        ushort8 x = *(const ushort8*)(S + (size_t)p.x * 128 + l16 * 8);
#pragma unroll
        for (int j = 0; j < 8; j++) a[j] = fmaf(b2f(x[j]), w, a[j]);
    }
#pragma unroll
    for (int j = 0; j < 8; j++) {
        a[j] += __shfl_xor(a[j], 16);
        a[j] += __shfl_xor(a[j], 32);
    }
    if (g4 == 0) {
        ushort8 o;
#pragma unroll
        for (int j = 0; j < 8; j++) o[j] = f2b(a[j]);
        *(ushort8*)(agg + (size_t)n * 128 + l16 * 8) = o;
    }
}

// ---------------- gather2 + add P (v8: packed edges) ----------------
__global__ __launch_bounds__(256) void gather_add(const int* __restrict__ row_start,
                                                  const uint2* __restrict__ epk,
                                                  const u16* __restrict__ T2,
                                                  const u16* __restrict__ P,
                                                  const int* __restrict__ flag,
                                                  void* __restrict__ out) {
    const int f32 = *flag;
    int n = blockIdx.x * 4 + (threadIdx.x >> 6);
    int lane = threadIdx.x & 63;
    int g4 = lane >> 4;
    int l16 = lane & 15;
    int s0 = row_start[n], s1 = row_start[n + 1];
    float a[8] = {0.f, 0.f, 0.f, 0.f, 0.f, 0.f, 0.f, 0.f};
    int e = s0;
    for (; e + 8 <= s1; e += 8) {
        uint2 p0 = epk[e + g4], p1 = epk[e + 4 + g4];
        float w0 = b2f((u16)p0.y), w1 = b2f((u16)p1.y);
        ushort8 x0 = *(const ushort8*)(T2 + (size_t)p0.x * 128 + l16 * 8);
        ushort8 x1 = *(const ushort8*)(T2 + (size_t)p1.x * 128 + l16 * 8);
#pragma unroll
        for (int j = 0; j < 8; j++) {
            a[j] = fmaf(b2f(x0[j]), w0, a[j]);
            a[j] = fmaf(b2f(x1[j]), w1, a[j]);
        }
    }
    for (; e + 4 <= s1; e += 4) {
        uint2 p = epk[e + g4];
        float w = b2f((u16)p.y);
        ushort8 x = *(const ushort8*)(T2 + (size_t)p.x * 128 + l16 * 8);
#pragma unroll
        for (int j = 0; j < 8; j++) a[j] = fmaf(b2f(x[j]), w, a[j]);
    }
    if (e < s1) {
        int eg = e + g4;
        int valid = eg < s1;
        uint2 p = epk[valid ? eg : s0];
        float w = valid ? b2f((u16)p.y) : 0.f;
        ushort8 x = *(const ushort8*)(T2 + (size_t)p.x * 128 + l16 * 8);
#pragma unroll
        for (int j = 0; j < 8; j++) a[j] = fmaf(b2f(x[j]), w, a[j]);
    }
#pragma unroll
    for (int j = 0; j < 8; j++) {
        a[j] += __shfl_xor(a[j], 16);
        a[j] += __shfl_xor(a[j], 32);
    }
    if (g4 == 0) {
        ushort8 pv = *(const ushort8*)(P + (size_t)n * 128 + l16 * 8);
        float v[8];
#pragma unroll
        for (int j = 0; j < 8; j++) v[j] = a[j] + b2f(pv[j]);
        if (f32) {
            float4 s0v, s1v;
            s0v.x = v[0]; s0v.y = v[1]; s0v.z = v[2]; s0v.w = v[3];
            s1v.x = v[4]; s1v.y = v[5]; s1v.z = v[6]; s1v.w = v[7];
            *(float4*)((float*)out + (size_t)n * 128 + l16 * 8) = s0v;
            *(float4*)((float*)out + (size_t)n * 128 + l16 * 8 + 4) = s1v;
        } else {
            ushort8 s;
#pragma unroll
            for (int j = 0; j < 8; j++) s[j] = f2b(v[j]);
            *(ushort8*)((u16*)out + (size_t)n * 128 + l16 * 8) = s;
        }
    }
}

// ---------------- fused dual MFMA GEMM (v6, UNCHANGED: 66us, VGPR 96) -------------
// Phase 1: H = relu([agg|Xb] @ Wf1 + b1)   (64 rows x 256 cols)
// Phase 2: [T2 | P] = H @ Wf2 (+b2 on P half)
// Block 256 thr = 4 waves side-by-side in columns; acc[4][4] = 64 regs/phase.
// LDSU (32 KB): A tile (XOR-swizzled, linear-dest DMA) -> H frags -> out tile.
// Epilogue-2: pack u16 tile in LDS (swizzled), then 8 coalesced 16B stores/thread.
__global__ __launch_bounds__(256) void fused_gemm(const u16* __restrict__ agg,
                                                  const u16* __restrict__ Xb,
                                                  const u16* __restrict__ Wf1,
                                                  const u16* __restrict__ Wf2,
                                                  const void* __restrict__ b1,
                                                  const void* __restrict__ b2,
                                                  u16* __restrict__ T2,
                                                  u16* __restrict__ P,
                                                  const int* __restrict__ flag,
                                                  int M) {
    const int f32 = *flag;
    __shared__ u16 LDSU[32 * 64 * 8];   // 32 KB: A tile -> H frags -> out tile
    const int row0 = blockIdx.x * 64;
    const int wid = threadIdx.x >> 6;   // wave = column quarter
    const int lane = threadIdx.x & 63;
    const int q = lane >> 4, lm = lane & 15;

    // ---- stage A tile (64 rows x K=256: chunks 0-15 agg, 16-31 Xb) ----
    {
        int kqL = lane & 31;
#pragma unroll
        for (int i = 0; i < 8; i++) {
            int t = i * 4 + wid;                   // wave-uniform instr index 0..31
            int row = 2 * t + (lane >> 5);         // 0..63
            int kqG = kqL ^ (row & 7);             // pre-swizzled source chunk
            const u16* src = (kqG < 16)
                ? agg + ((size_t)(row0 + row)) * 128 + kqG * 8
                : Xb + ((size_t)(row0 + row)) * 128 + (kqG - 16) * 8;
            gload_lds16(src, LDSU + (size_t)t * 512);
        }
    }
    __syncthreads();   // drains vmcnt (global_load_lds) before any ds_read

    // ---- phase 1: MFMAs only (epilogue deferred so LDSU can be reused) ----
    float4v acc[4][4];   // [ti rows][tj cols]
#pragma unroll
    for (int i = 0; i < 4; i++)
#pragma unroll
        for (int j = 0; j < 4; j++) acc[i][j] = (float4v){0.f, 0.f, 0.f, 0.f};
#pragma unroll
    for (int kb = 0; kb < 8; kb++) {
        short8 a[4];
#pragma unroll
        for (int ti = 0; ti < 4; ti++) {
            int rl = ti * 16 + lm;
            int chunk = (kb * 4 + q) ^ (rl & 7);   // XOR-swizzle read side
            a[ti] = *(const short8*)(LDSU + (size_t)rl * 256 + chunk * 8);
        }
        short8 b[4];
#pragma unroll
        for (int tj = 0; tj < 4; tj++) {
            int nt = wid * 4 + tj;
            b[tj] = *(const short8*)(Wf1 + ((size_t)(nt * 8 + kb) * 64 + lane) * 8);
        }
#pragma unroll
        for (int ti = 0; ti < 4; ti++)
#pragma unroll
            for (int tj = 0; tj < 4; tj++)
                acc[ti][tj] = __builtin_amdgcn_mfma_f32_16x16x32_bf16(
                    a[ti], b[tj], acc[ti][tj], 0, 0, 0);
    }
    __syncthreads();   // all A reads done; LDSU now reusable for H

    // ---- phase-1 epilogue: bias + relu -> LDSU (phase-2 A-frag order) ----
#pragma unroll
    for (int tj = 0; tj < 4; tj++) {
        int col = wid * 64 + tj * 16 + lm;
        float bv = lde(b1, col, f32);
        int kq2 = col >> 3, jj = col & 7;
#pragma unroll
        for (int ti = 0; ti < 4; ti++) {
            int rl = ti * 16 + q * 4;
#pragma unroll
            for (int r = 0; r < 4; r++) {
                float v = fmaxf(acc[ti][tj][r] + bv, 0.f);
                LDSU[((size_t)kq2 * 64 + rl + r) * 8 + jj] = f2b(v);
            }
        }
    }
    __syncthreads();

    // ---- phase 2 ----
    float4v acc2[4][4];
#pragma unroll
    for (int i = 0; i < 4; i++)
#pragma unroll
        for (int j = 0; j < 4; j++) acc2[i][j] = (float4v){0.f, 0.f, 0.f, 0.f};
#pragma unroll
    for (int kb = 0; kb < 8; kb++) {
        short8 a[4];
#pragma unroll
        for (int ti = 0; ti < 4; ti++) {
            int rl = ti * 16 + lm;
            a[ti] = *(const short8*)(LDSU + ((size_t)(kb * 4 + q) * 64 + rl) * 8);
        }
        short8 b[4];
#pragma unroll
        for (int tj = 0; tj < 4; tj++) {
            int nt = wid * 4 + tj;
            b[tj] = *(const short8*)(Wf2 + ((size_t)(nt * 8 + kb) * 64 + lane) * 8);
        }
#pragma unroll
        for (int ti = 0; ti < 4; ti++)
#pragma unroll
            for (int tj = 0; tj < 4; tj++)
                acc2[ti][tj] = __builtin_amdgcn_mfma_f32_16x16x32_bf16(
                    a[ti], b[tj], acc2[ti][tj], 0, 0, 0);
    }
    __syncthreads();   // all H reads done; LDSU now reusable for output tile

    // ---- phase-2 epilogue: pack [64 r][256 c] u16 tile in LDS, then wide stores ----
#pragma unroll
    for (int tj = 0; tj < 4; tj++) {
        int col = wid * 64 + tj * 16 + lm;
        int chunk = col >> 3, jj = col & 7;
        float bv = (col < 128) ? 0.f : lde(b2, col - 128, f32);
#pragma unroll
        for (int ti = 0; ti < 4; ti++) {
#pragma unroll
            for (int r = 0; r < 4; r++) {
                int row = ti * 16 + q * 4 + r;
                int pchunk = chunk ^ (((row >> 2) & 3) << 1);  // q -> bank bits
                LDSU[((size_t)row * 32 + pchunk) * 8 + jj] = f2b(acc2[ti][tj][r] + bv);
            }
        }
    }
    __syncthreads();
#pragma unroll
    for (int i = 0; i < 8; i++) {
        int g = i * 256 + threadIdx.x;      // 0..2047 16B-chunks of the tile
        int row = g >> 5;                   // 0..63
        int chunk = g & 31;
        int pchunk = chunk ^ (((row >> 2) & 3) << 1);
        short8 v = *(const short8*)(LDSU + ((size_t)row * 32 + pchunk) * 8);
        int grow = row0 + row;
        int colu = chunk * 8;
        u16* dst = (colu < 128) ? (T2 + (size_t)grow * 128 + colu)
                                : (P + (size_t)grow * 128 + (colu - 128));
        *(short8*)dst = v;
    }
    (void)M;
}

extern "C" void kernel_launch(void* const* d_in, const int* in_sizes, int n_in,
                              void* d_out, int out_size, void* d_ws, size_t ws_size,
                              hipStream_t stream) {
    const void* pf     = d_in[0];
    const int*  sid    = (const int*)d_in[1];
    const int*  ei     = (const int*)d_in[2];
    const void* ew     = d_in[3];
    const void* Wp     = d_in[4];
    const void* bp     = d_in[5];
    const void* semb   = d_in[6];
    const void* et     = d_in[7];
    const void* W1rel  = d_in[8];
    const void* b1     = d_in[9];
    const void* W1root = d_in[10];
    const void* W2rel  = d_in[11];
    const void* b2     = d_in[12];
    const void* W2root = d_in[13];

    // Workspace (~113.1 MB < proven 122.88 MB budget):
    char* w = (char*)d_ws;
    u16*   agg       = (u16*)w;                    // bf16 [N,128]
    u16*   T2        = (u16*)(w + 30720000);       // bf16 [N,128]
    u16*   P         = (u16*)(w + 61440000);       // bf16 [N,128]
    u16*   Wf1       = (u16*)(w + 92160000);       // 131072 B
    u16*   Wf2       = (u16*)(w + 92291072);       // 131072 B
    uint2* epk       = (uint2*)(w + 92422144);     // packed {src,w} [E] = 8 MB
    int*   rank      = (int*)(w + 100422144);      // int [E] = 4 MB
    int*   row_start = (int*)(w + 104422144);      // int [N+1]
    int*   row_tmp   = (int*)(w + 104902148);      // int [N]
    int*   count     = (int*)(w + 105382148);      // int [NREP][N] = 3.84 MB
    int*   roff      = (int*)(w + 109222148);      // int [NREP][N] = 3.84 MB
    int*   bsum      = (int*)(w + 113062148);      // int [512]
    int*   flag      = (int*)(w + 113066244);      // dtype flag
    u16*   Xb        = (u16*)d_out;                // bf16 [N,128] scratch until fused_gemm done

    const int NB = (NNODE + 255) / 256;   // 469
    const int GB = (NNODE + 63) / 64;     // 1875
    const int ZB = (NREP * NNODE + 255) / 256;   // 3750

    // dtype detection + count zeroing (one dispatch)
    detect_k<<<ZB, 256, 0, stream>>>(ew, flag, count);

    // hist (4 edges/thread, 4x atomic MLP) || build_x (streaming backfill)
    hist_build<<<HB + POLB + TICKB, 256, 0, stream>>>(
        ei, count, rank, pf, sid, Wp, bp, semb, et, flag, Xb);

    scan1<<<NB, 256, 0, stream>>>(count, roff, row_tmp, bsum);
    scan2<<<1, 512, 0, stream>>>(bsum, NB);
    scan3<<<NB, 256, 0, stream>>>(row_tmp, bsum, row_start);

    // fill_csr (critical path) || prep_wf (backfill)
    fill_prep<<<EB + 512, 256, 0, stream>>>(ei, ew, flag, row_start, roff, rank, epk,
                                            W1rel, W1root, W2rel, W2root, Wf1, Wf2);

    // layer-1 aggregation
    gather128<<<NNODE / 4, 256, 0, stream>>>(row_start, epk, Xb, agg);

    // fused: H = relu([agg|Xb]@Wf1+b1) in LDS; [T2|P] = H@Wf2 (+b2 on P)
    fused_gemm<<<GB, 256, 0, stream>>>(agg, Xb, Wf1, Wf2, b1, b2, T2, P, flag, NNODE);

    // out = P + segment_sum(w * T2)   (d_out scratch Xb is dead now)
    gather_add<<<NNODE / 4, 256, 0, stream>>>(row_start, epk, T2, P, flag, d_out);
}

// Round 16
// 331.729 us; speedup vs baseline: 1.1595x; 1.1595x over previous
//
#include <hip/hip_runtime.h>
#include <hip/hip_bf16.h>

typedef unsigned short u16;
using short8  = __attribute__((ext_vector_type(8))) short;
using ushort8 = __attribute__((ext_vector_type(8))) unsigned short;
using float4v = __attribute__((ext_vector_type(4))) float;

#define N_POL  100000
#define N_TICK 20000
#define NNODE  120000
#define NEDGE  1000000
#define NBLK   977      // level-1 blocks: (NEDGE/4 + 255)/256, 1024 edges/block
#define NBKT2  235      // level-2 blocks: (NNODE + 511)/512
#define POLB   50000    // N_POL/2
#define TICKB  10000    // N_TICK*128/256
// EMB=128, HID=256, OUT=128

static __device__ __forceinline__ float b2f(u16 u) {
    return __uint_as_float(((unsigned)u) << 16);
}
static __device__ __forceinline__ u16 f2b(float f) {
    unsigned u = __float_as_uint(f);
    unsigned r = (u + 0x7FFFu + ((u >> 16) & 1u)) >> 16;
    return (u16)r;
}
static __device__ __forceinline__ float lde(const void* p, size_t i, int f32) {
    return f32 ? ((const float*)p)[i] : b2f(((const u16*)p)[i]);
}

// MFMA B-fragment address for K=256, N=256 packed weights (verified R7):
// element (k,n) -> ((n/16)*8 + k/32)*512 + (((k>>3)&3)*16 + (n&15))*8 + (k&7)
static __device__ __forceinline__ size_t frag_addr(int k, int n) {
    return ((size_t)((n >> 4) * 8 + (k >> 5)) * 64 + (((k >> 3) & 3) * 16 + (n & 15))) * 8
           + (k & 7);
}

// 16B global->LDS DMA (wave-uniform LDS base; HW adds lane*16)
static __device__ __forceinline__ void gload_lds16(const u16* g, u16* l) {
    __builtin_amdgcn_global_load_lds(
        (const __attribute__((address_space(1))) void*)g,
        (__attribute__((address_space(3))) void*)l, 16, 0, 0);
}

// ---------------- one-shot input-dtype detection ----------------
// Runtime input-dtype detection on edge_weight (uniform [0,1)). See R4/R5 notes.
__global__ void detect_k(const void* __restrict__ ew, int* __restrict__ flag) {
    if (threadIdx.x == 0) {
        const u16* p = (const u16*)ew;
        int huge = 0, allz = 1;
        for (int j = 0; j < 128; j += 2) {
            u16 b = p[j];
            if (b != 0) allz = 0;
            float v = b2f(b);
            if (!(fabsf(v) <= 4.0f)) huge = 1;
        }
        *flag = huge | allz;
    }
}

// ================= CSR build v12: two-level bucket sort, LDS atomics only =========
// r13/r15 established: 1M device-scope atomicAdd-with-return = ~15 G/s wall (~66-85us)
// regardless of MLP or replication (memory-side execution; 32B write-through per op).
// This path has ZERO fabric atomics. Level 1: bucket = dst>>9 (256 bins, LDS hist),
// scatter to bucket-contiguous tmp1. Level 2: per-bucket 512-bin LDS counting sort
// -> row_start + epk (formats unchanged; within-dst order arbitrary, gathers sum).

// L1 histogram: per-block 256-bin LDS hist -> bh[bucket][block] (bucket-major).
__global__ __launch_bounds__(256) void p1hist(const int* __restrict__ ei,
                                              int* __restrict__ bh) {
    __shared__ int h[256];
    int t = threadIdx.x;
    h[t] = 0;
    __syncthreads();
    int e0 = (blockIdx.x * 256 + t) * 4;
    if (e0 + 4 <= NEDGE) {
        int4 d = *(const int4*)(ei + NEDGE + e0);
        atomicAdd(&h[d.x >> 9], 1);
        atomicAdd(&h[d.y >> 9], 1);
        atomicAdd(&h[d.z >> 9], 1);
        atomicAdd(&h[d.w >> 9], 1);
    } else {
        for (int e = e0; e < NEDGE; e++)
            atomicAdd(&h[ei[NEDGE + e] >> 9], 1);
    }
    __syncthreads();
    bh[t * NBLK + blockIdx.x] = h[t];
}

// L1 scan A: per bucket, exclusive scan over its NBLK block-counts (in place);
// bucket total -> btot.
__global__ __launch_bounds__(256) void p1scanA(int* __restrict__ bh,
                                               int* __restrict__ btot) {
    __shared__ int sd[256];
    int b = blockIdx.x;
    int t = threadIdx.x;
    int base = b * NBLK;
    int v[4]; int tot = 0;
    int j0 = t * 4;
#pragma unroll
    for (int k = 0; k < 4; k++) {
        int j = j0 + k;
        v[k] = (j < NBLK) ? bh[base + j] : 0;
        tot += v[k];
    }
    sd[t] = tot;
    __syncthreads();
#pragma unroll
    for (int off = 1; off < 256; off <<= 1) {
        int u = (t >= off) ? sd[t - off] : 0;
        __syncthreads();
        sd[t] += u;
        __syncthreads();
    }
    int excl = sd[t] - tot;
#pragma unroll
    for (int k = 0; k < 4; k++) {
        int j = j0 + k;
        if (j < NBLK) { int tmp = v[k]; bh[base + j] = excl; excl += tmp; }
    }
    if (t == 255) btot[b] = sd[255];
}

// L1 scan B: exclusive scan of 256 bucket totals -> bbase[0..256]; also seeds
// row_start[NNODE] = NEDGE.
__global__ void p1scanB(const int* __restrict__ btot, int* __restrict__ bbase,
                        int* __restrict__ row_start) {
    __shared__ int sd[256];
    int t = threadIdx.x;
    int v = btot[t];
    sd[t] = v;
    __syncthreads();
#pragma unroll
    for (int off = 1; off < 256; off <<= 1) {
        int u = (t >= off) ? sd[t - off] : 0;
        __syncthreads();
        sd[t] += u;
        __syncthreads();
    }
    bbase[t] = sd[t] - v;
    if (t == 255) { bbase[256] = sd[255]; row_start[NNODE] = NEDGE; }
}

// L1 scatter (blocks [0,NBLK)) + build_x backfill (blocks after).
// Scatter: slot = bbase[bucket] + bh[bucket][block] + LDS-cursor rank.
// tmp1 record: {src, (w16<<16)|(dst&511)}.
__global__ __launch_bounds__(256) void p1scat_build(const int* __restrict__ ei,
                                                    const void* __restrict__ ew,
                                                    const int* __restrict__ flag,
                                                    const int* __restrict__ bh,
                                                    const int* __restrict__ bbase,
                                                    uint2* __restrict__ tmp1,
                                                    const void* __restrict__ pf,
                                                    const int* __restrict__ sid,
                                                    const void* __restrict__ Wp,
                                                    const void* __restrict__ bp,
                                                    const void* __restrict__ semb,
                                                    const void* __restrict__ et,
                                                    u16* __restrict__ Xb) {
    const int f32 = *flag;
    if (blockIdx.x < NBLK) {
        __shared__ int base[256];
        __shared__ int cur[256];
        int t = threadIdx.x;
        base[t] = bbase[t] + bh[t * NBLK + blockIdx.x];
        cur[t] = 0;
        __syncthreads();
        int e0 = (blockIdx.x * 256 + t) * 4;
#pragma unroll
        for (int k = 0; k < 4; k++) {
            int e = e0 + k;
            if (e < NEDGE) {
                int dst = ei[NEDGE + e];
                int o = dst >> 9;
                int src = ei[e];
                unsigned w16 = (unsigned)f2b(lde(ew, e, f32));
                int r = atomicAdd(&cur[o], 1);
                uint2 u;
                u.x = (unsigned)src;
                u.y = (w16 << 16) | (unsigned)(dst & 511);
                tmp1[base[o] + r] = u;
            }
        }
        return;
    }
    int bb = blockIdx.x - NBLK;
    if (bb < POLB) {
        int row = bb * 2 + (threadIdx.x >> 7);
        int j = threadIdx.x & 127;
        float s = lde(bp, j, f32);
#pragma unroll
        for (int k = 0; k < 7; k++)
            s = fmaf(lde(pf, (size_t)row * 7 + k, f32), lde(Wp, k * 128 + j, f32), s);
        s = fmaxf(s, 0.f);
        s += lde(semb, (size_t)sid[row] * 128 + j, f32);
        Xb[(size_t)row * 128 + j] = f2b(s);
    } else {
        int idx = (bb - POLB) * 256 + threadIdx.x;
        Xb[(size_t)N_POL * 128 + idx] = f2b(lde(et, idx, f32));
    }
}

// L2 (blocks [0,NBKT2)): per-bucket 512-bin LDS counting sort -> row_start + epk.
// Blocks [NBKT2, NBKT2+512): prep_wf backfill.
__global__ __launch_bounds__(256) void p2_prep(const uint2* __restrict__ tmp1,
                                               const int* __restrict__ bbase,
                                               uint2* __restrict__ epk,
                                               int* __restrict__ row_start,
                                               const void* __restrict__ W1rel,
                                               const void* __restrict__ W1root,
                                               const void* __restrict__ W2rel,
                                               const void* __restrict__ W2root,
                                               const int* __restrict__ flag,
                                               u16* __restrict__ Wf1,
                                               u16* __restrict__ Wf2) {
    if (blockIdx.x < NBKT2) {
        __shared__ int h[512];
        __shared__ int sc[512];
        int b = blockIdx.x;
        int t = threadIdx.x;
        h[t] = 0; h[t + 256] = 0;
        __syncthreads();
        int lo = bbase[b], hi = bbase[b + 1];
        for (int i = lo + t; i < hi; i += 256)
            atomicAdd(&h[tmp1[i].y & 511], 1);
        __syncthreads();
        sc[t] = h[t]; sc[t + 256] = h[t + 256];
        __syncthreads();
#pragma unroll
        for (int off = 1; off < 512; off <<= 1) {
            int v0 = (t >= off) ? sc[t - off] : 0;
            int v1 = (t + 256 >= off) ? sc[t + 256 - off] : 0;
            __syncthreads();
            sc[t] += v0; sc[t + 256] += v1;
            __syncthreads();
        }
        int e0_ = sc[t] - h[t];             // exclusive offsets within bucket
        int e1_ = sc[t + 256] - h[t + 256];
        int node0 = b * 512;
        if (node0 + t < NNODE) row_start[node0 + t] = lo + e0_;
        if (node0 + t + 256 < NNODE) row_start[node0 + t + 256] = lo + e1_;
        __syncthreads();                    // all h reads done before reuse as cursor
        h[t] = e0_; h[t + 256] = e1_;
        __syncthreads();
        for (int i = lo + t; i < hi; i += 256) {
            uint2 u = tmp1[i];
            int j = (int)(u.y & 511u);
            int r = atomicAdd(&h[j], 1);
            uint2 o;
            o.x = u.x;
            o.y = u.y >> 16;                // w16
            epk[lo + r] = o;
        }
        return;
    }
    const int f32 = *flag;
    int idx = (blockIdx.x - NBKT2) * 256 + threadIdx.x;   // 0..131071
    int id = idx & 65535;
    int k = id >> 8, n = id & 255;
    if (idx < 65536) {
        float v = (k < 128) ? lde(W1rel, (size_t)k * 256 + n, f32)
                            : lde(W1root, (size_t)(k - 128) * 256 + n, f32);
        Wf1[frag_addr(k, n)] = f2b(v);
    } else {
        float v = (n < 128) ? lde(W2rel, (size_t)k * 128 + n, f32)
                            : lde(W2root, (size_t)k * 128 + (n - 128), f32);
        Wf2[frag_addr(k, n)] = f2b(v);
    }
}

// ---------------- gather1 (v8: packed edges; 4 edges/wave, 16B/lane) --------
__global__ __launch_bounds__(256) void gather128(const int* __restrict__ row_start,
                                                 const uint2* __restrict__ epk,
                                                 const u16* __restrict__ S,
                                                 u16* __restrict__ agg) {
    int n = blockIdx.x * 4 + (threadIdx.x >> 6);
    int lane = threadIdx.x & 63;
    int g4 = lane >> 4;        // edge slot 0..3
    int l16 = lane & 15;       // 16B chunk within the row
    int s0 = row_start[n], s1 = row_start[n + 1];
    float a[8] = {0.f, 0.f, 0.f, 0.f, 0.f, 0.f, 0.f, 0.f};
    int e = s0;
    for (; e + 8 <= s1; e += 8) {
        uint2 p0 = epk[e + g4], p1 = epk[e + 4 + g4];
        float w0 = b2f((u16)p0.y), w1 = b2f((u16)p1.y);
        ushort8 x0 = *(const ushort8*)(S + (size_t)p0.x * 128 + l16 * 8);
        ushort8 x1 = *(const ushort8*)(S + (size_t)p1.x * 128 + l16 * 8);
#pragma unroll
        for (int j = 0; j < 8; j++) {
            a[j] = fmaf(b2f(x0[j]), w0, a[j]);
            a[j] = fmaf(b2f(x1[j]), w1, a[j]);
        }
    }
    for (; e + 4 <= s1; e += 4) {
        uint2 p = epk[e + g4];
        float w = b2f((u16)p.y);
        ushort8 x = *(const ushort8*)(S + (size_t)p.x * 128 + l16 * 8);
#pragma unroll
        for (int j = 0; j < 8; j++) a[j] = fmaf(b2f(x[j]), w, a[j]);
    }
    if (e < s1) {
        int eg = e + g4;
        int valid = eg < s1;
        uint2 p = epk[valid ? eg : s0];    // s0 < s1 here, safe
        float w = valid ? b2f((u16)p.y) : 0.f;
        ushort8 x = *(const ushort8*)(S + (size_t)p.x * 128 + l16 * 8);
#pragma unroll
        for (int j = 0; j < 8; j++) a[j] = fmaf(b2f(x[j]), w, a[j]);
    }
#pragma unroll
    for (int j = 0; j < 8; j++) {
        a[j] += __shfl_xor(a[j], 16);
        a[j] += __shfl_xor(a[j], 32);
    }
    if (g4 == 0) {
        ushort8 o;
#pragma unroll
        for (int j = 0; j < 8; j++) o[j] = f2b(a[j]);
        *(ushort8*)(agg + (size_t)n * 128 + l16 * 8) = o;
    }
}

// ---------------- gather2 + add P (v8: packed edges) ----------------
__global__ __launch_bounds__(256) void gather_add(const int* __restrict__ row_start,
                                                  const uint2* __restrict__ epk,
                                                  const u16* __restrict__ T2,
                                                  const u16* __restrict__ P,
                                                  const int* __restrict__ flag,
                                                  void* __restrict__ out) {
    const int f32 = *flag;
    int n = blockIdx.x * 4 + (threadIdx.x >> 6);
    int lane = threadIdx.x & 63;
    int g4 = lane >> 4;
    int l16 = lane & 15;
    int s0 = row_start[n], s1 = row_start[n + 1];
    float a[8] = {0.f, 0.f, 0.f, 0.f, 0.f, 0.f, 0.f, 0.f};
    int e = s0;
    for (; e + 8 <= s1; e += 8) {
        uint2 p0 = epk[e + g4], p1 = epk[e + 4 + g4];
        float w0 = b2f((u16)p0.y), w1 = b2f((u16)p1.y);
        ushort8 x0 = *(const ushort8*)(T2 + (size_t)p0.x * 128 + l16 * 8);
        ushort8 x1 = *(const ushort8*)(T2 + (size_t)p1.x * 128 + l16 * 8);
#pragma unroll
        for (int j = 0; j < 8; j++) {
            a[j] = fmaf(b2f(x0[j]), w0, a[j]);
            a[j] = fmaf(b2f(x1[j]), w1, a[j]);
        }
    }
    for (; e + 4 <= s1; e += 4) {
        uint2 p = epk[e + g4];
        float w = b2f((u16)p.y);
        ushort8 x = *(const ushort8*)(T2 + (size_t)p.x * 128 + l16 * 8);
#pragma unroll
        for (int j = 0; j < 8; j++) a[j] = fmaf(b2f(x[j]), w, a[j]);
    }
    if (e < s1) {
        int eg = e + g4;
        int valid = eg < s1;
        uint2 p = epk[valid ? eg : s0];
        float w = valid ? b2f((u16)p.y) : 0.f;
        ushort8 x = *(const ushort8*)(T2 + (size_t)p.x * 128 + l16 * 8);
#pragma unroll
        for (int j = 0; j < 8; j++) a[j] = fmaf(b2f(x[j]), w, a[j]);
    }
#pragma unroll
    for (int j = 0; j < 8; j++) {
        a[j] += __shfl_xor(a[j], 16);
        a[j] += __shfl_xor(a[j], 32);
    }
    if (g4 == 0) {
        ushort8 pv = *(const ushort8*)(P + (size_t)n * 128 + l16 * 8);
        float v[8];
#pragma unroll
        for (int j = 0; j < 8; j++) v[j] = a[j] + b2f(pv[j]);
        if (f32) {
            float4 s0v, s1v;
            s0v.x = v[0]; s0v.y = v[1]; s0v.z = v[2]; s0v.w = v[3];
            s1v.x = v[4]; s1v.y = v[5]; s1v.z = v[6]; s1v.w = v[7];
            *(float4*)((float*)out + (size_t)n * 128 + l16 * 8) = s0v;
            *(float4*)((float*)out + (size_t)n * 128 + l16 * 8 + 4) = s1v;
        } else {
            ushort8 s;
#pragma unroll
            for (int j = 0; j < 8; j++) s[j] = f2b(v[j]);
            *(ushort8*)((u16*)out + (size_t)n * 128 + l16 * 8) = s;
        }
    }
}

// ---------------- fused dual MFMA GEMM (v6, UNCHANGED: 66us, VGPR 96) -------------
// Phase 1: H = relu([agg|Xb] @ Wf1 + b1)   (64 rows x 256 cols)
// Phase 2: [T2 | P] = H @ Wf2 (+b2 on P half)
// Block 256 thr = 4 waves side-by-side in columns; acc[4][4] = 64 regs/phase.
// LDSU (32 KB): A tile (XOR-swizzled, linear-dest DMA) -> H frags -> out tile.
// Epilogue-2: pack u16 tile in LDS (swizzled), then 8 coalesced 16B stores/thread.
__global__ __launch_bounds__(256) void fused_gemm(const u16* __restrict__ agg,
                                                  const u16* __restrict__ Xb,
                                                  const u16* __restrict__ Wf1,
                                                  const u16* __restrict__ Wf2,
                                                  const void* __restrict__ b1,
                                                  const void* __restrict__ b2,
                                                  u16* __restrict__ T2,
                                                  u16* __restrict__ P,
                                                  const int* __restrict__ flag,
                                                  int M) {
    const int f32 = *flag;
    __shared__ u16 LDSU[32 * 64 * 8];   // 32 KB: A tile -> H frags -> out tile
    const int row0 = blockIdx.x * 64;
    const int wid = threadIdx.x >> 6;   // wave = column quarter
    const int lane = threadIdx.x & 63;
    const int q = lane >> 4, lm = lane & 15;

    // ---- stage A tile (64 rows x K=256: chunks 0-15 agg, 16-31 Xb) ----
    {
        int kqL = lane & 31;
#pragma unroll
        for (int i = 0; i < 8; i++) {
            int t = i * 4 + wid;                   // wave-uniform instr index 0..31
            int row = 2 * t + (lane >> 5);         // 0..63
            int kqG = kqL ^ (row & 7);             // pre-swizzled source chunk
            const u16* src = (kqG < 16)
                ? agg + ((size_t)(row0 + row)) * 128 + kqG * 8
                : Xb + ((size_t)(row0 + row)) * 128 + (kqG - 16) * 8;
            gload_lds16(src, LDSU + (size_t)t * 512);
        }
    }
    __syncthreads();   // drains vmcnt (global_load_lds) before any ds_read

    // ---- phase 1: MFMAs only (epilogue deferred so LDSU can be reused) ----
    float4v acc[4][4];   // [ti rows][tj cols]
#pragma unroll
    for (int i = 0; i < 4; i++)
#pragma unroll
        for (int j = 0; j < 4; j++) acc[i][j] = (float4v){0.f, 0.f, 0.f, 0.f};
#pragma unroll
    for (int kb = 0; kb < 8; kb++) {
        short8 a[4];
#pragma unroll
        for (int ti = 0; ti < 4; ti++) {
            int rl = ti * 16 + lm;
            int chunk = (kb * 4 + q) ^ (rl & 7);   // XOR-swizzle read side
            a[ti] = *(const short8*)(LDSU + (size_t)rl * 256 + chunk * 8);
        }
        short8 b[4];
#pragma unroll
        for (int tj = 0; tj < 4; tj++) {
            int nt = wid * 4 + tj;
            b[tj] = *(const short8*)(Wf1 + ((size_t)(nt * 8 + kb) * 64 + lane) * 8);
        }
#pragma unroll
        for (int ti = 0; ti < 4; ti++)
#pragma unroll
            for (int tj = 0; tj < 4; tj++)
                acc[ti][tj] = __builtin_amdgcn_mfma_f32_16x16x32_bf16(
                    a[ti], b[tj], acc[ti][tj], 0, 0, 0);
    }
    __syncthreads();   // all A reads done; LDSU now reusable for H

    // ---- phase-1 epilogue: bias + relu -> LDSU (phase-2 A-frag order) ----
#pragma unroll
    for (int tj = 0; tj < 4; tj++) {
        int col = wid * 64 + tj * 16 + lm;
        float bv = lde(b1, col, f32);
        int kq2 = col >> 3, jj = col & 7;
#pragma unroll
        for (int ti = 0; ti < 4; ti++) {
            int rl = ti * 16 + q * 4;
#pragma unroll
            for (int r = 0; r < 4; r++) {
                float v = fmaxf(acc[ti][tj][r] + bv, 0.f);
                LDSU[((size_t)kq2 * 64 + rl + r) * 8 + jj] = f2b(v);
            }
        }
    }
    __syncthreads();

    // ---- phase 2 ----
    float4v acc2[4][4];
#pragma unroll
    for (int i = 0; i < 4; i++)
#pragma unroll
        for (int j = 0; j < 4; j++) acc2[i][j] = (float4v){0.f, 0.f, 0.f, 0.f};
#pragma unroll
    for (int kb = 0; kb < 8; kb++) {
        short8 a[4];
#pragma unroll
        for (int ti = 0; ti < 4; ti++) {
            int rl = ti * 16 + lm;
            a[ti] = *(const short8*)(LDSU + ((size_t)(kb * 4 + q) * 64 + rl) * 8);
        }
        short8 b[4];
#pragma unroll
        for (int tj = 0; tj < 4; tj++) {
            int nt = wid * 4 + tj;
            b[tj] = *(const short8*)(Wf2 + ((size_t)(nt * 8 + kb) * 64 + lane) * 8);
        }
#pragma unroll
        for (int ti = 0; ti < 4; ti++)
#pragma unroll
            for (int tj = 0; tj < 4; tj++)
                acc2[ti][tj] = __builtin_amdgcn_mfma_f32_16x16x32_bf16(
                    a[ti], b[tj], acc2[ti][tj], 0, 0, 0);
    }
    __syncthreads();   // all H reads done; LDSU now reusable for output tile

    // ---- phase-2 epilogue: pack [64 r][256 c] u16 tile in LDS, then wide stores ----
#pragma unroll
    for (int tj = 0; tj < 4; tj++) {
        int col = wid * 64 + tj * 16 + lm;
        int chunk = col >> 3, jj = col & 7;
        float bv = (col < 128) ? 0.f : lde(b2, col - 128, f32);
#pragma unroll
        for (int ti = 0; ti < 4; ti++) {
#pragma unroll
            for (int r = 0; r < 4; r++) {
                int row = ti * 16 + q * 4 + r;
                int pchunk = chunk ^ (((row >> 2) & 3) << 1);  // q -> bank bits
                LDSU[((size_t)row * 32 + pchunk) * 8 + jj] = f2b(acc2[ti][tj][r] + bv);
            }
        }
    }
    __syncthreads();
#pragma unroll
    for (int i = 0; i < 8; i++) {
        int g = i * 256 + threadIdx.x;      // 0..2047 16B-chunks of the tile
        int row = g >> 5;                   // 0..63
        int chunk = g & 31;
        int pchunk = chunk ^ (((row >> 2) & 3) << 1);
        short8 v = *(const short8*)(LDSU + ((size_t)row * 32 + pchunk) * 8);
        int grow = row0 + row;
        int colu = chunk * 8;
        u16* dst = (colu < 128) ? (T2 + (size_t)grow * 128 + colu)
                                : (P + (size_t)grow * 128 + (colu - 128));
        *(short8*)dst = v;
    }
    (void)M;
}

extern "C" void kernel_launch(void* const* d_in, const int* in_sizes, int n_in,
                              void* d_out, int out_size, void* d_ws, size_t ws_size,
                              hipStream_t stream) {
    const void* pf     = d_in[0];
    const int*  sid    = (const int*)d_in[1];
    const int*  ei     = (const int*)d_in[2];
    const void* ew     = d_in[3];
    const void* Wp     = d_in[4];
    const void* bp     = d_in[5];
    const void* semb   = d_in[6];
    const void* et     = d_in[7];
    const void* W1rel  = d_in[8];
    const void* b1     = d_in[9];
    const void* W1root = d_in[10];
    const void* W2rel  = d_in[11];
    const void* b2     = d_in[12];
    const void* W2root = d_in[13];

    // Workspace (~109.9 MB < proven 122.88 MB budget):
    char* w = (char*)d_ws;
    u16*   agg       = (u16*)w;                    // bf16 [N,128]
    u16*   T2        = (u16*)(w + 30720000);       // bf16 [N,128]
    u16*   P         = (u16*)(w + 61440000);       // bf16 [N,128]
    u16*   Wf1       = (u16*)(w + 92160000);       // 131072 B
    u16*   Wf2       = (u16*)(w + 92291072);       // 131072 B
    uint2* epk       = (uint2*)(w + 92422144);     // packed {src,w} [E] = 8 MB
    uint2* tmp1      = (uint2*)(w + 100422144);    // bucket-sorted stage = 8 MB
    int*   bh        = (int*)(w + 108422144);      // [256][NBLK] = 1.0 MB
    int*   btot      = (int*)(w + 109422592);      // [256]
    int*   bbase     = (int*)(w + 109423616);      // [257]
    int*   row_start = (int*)(w + 109424648);      // int [N+1]
    int*   flag      = (int*)(w + 109904652);      // dtype flag
    u16*   Xb        = (u16*)d_out;                // bf16 [N,128] scratch until fused_gemm done

    const int GB = (NNODE + 63) / 64;     // 1875

    // dtype detection
    detect_k<<<1, 64, 0, stream>>>(ew, flag);

    // CSR build v12: two-level bucket sort, LDS atomics only (no fabric atomics)
    p1hist<<<NBLK, 256, 0, stream>>>(ei, bh);
    p1scanA<<<256, 256, 0, stream>>>(bh, btot);
    p1scanB<<<1, 256, 0, stream>>>(btot, bbase, row_start);
    // L1 scatter (critical path) || build_x backfill
    p1scat_build<<<NBLK + POLB + TICKB, 256, 0, stream>>>(
        ei, ew, flag, bh, bbase, tmp1, pf, sid, Wp, bp, semb, et, Xb);
    // L2 counting sort -> row_start + epk || prep_wf backfill
    p2_prep<<<NBKT2 + 512, 256, 0, stream>>>(tmp1, bbase, epk, row_start,
                                             W1rel, W1root, W2rel, W2root, flag,
                                             Wf1, Wf2);

    // layer-1 aggregation
    gather128<<<NNODE / 4, 256, 0, stream>>>(row_start, epk, Xb, agg);

    // fused: H = relu([agg|Xb]@Wf1+b1) in LDS; [T2|P] = H@Wf2 (+b2 on P)
    fused_gemm<<<GB, 256, 0, stream>>>(agg, Xb, Wf1, Wf2, b1, b2, T2, P, flag, NNODE);

    // out = P + segment_sum(w * T2)   (d_out scratch Xb is dead now)
    gather_add<<<NNODE / 4, 256, 0, stream>>>(row_start, epk, T2, P, flag, d_out);
}